// Round 5
// baseline (829.912 us; speedup 1.0000x reference)
//
#include <hip/hip_runtime.h>

#define T_TOK 4096
#define D_DIM 1024
#define E_EXP 8
#define H_DIM 2048
#define CAP   10240  // 8192 slots + 8*256 tile padding (BM=256)
#define TILES_M 40   // CAP/256

typedef __attribute__((ext_vector_type(8))) short bf16x8;
typedef __attribute__((ext_vector_type(4))) float f32x4;

__device__ inline unsigned short f2bf(float f) {
    unsigned int u = __float_as_uint(f);
    unsigned int r = (u + 0x7fffu + ((u >> 16) & 1u)) >> 16;
    return (unsigned short)r;
}

#define GLD_LDS16(g, l)                                                        \
    __builtin_amdgcn_global_load_lds(                                          \
        (const __attribute__((address_space(1))) void*)(g),                    \
        (__attribute__((address_space(3))) void*)(l), 16, 0, 0)

// ------------- fp32 (R,C) -> bf16 transposed (C,R), per expert -------------
__global__ __launch_bounds__(256) void tcvt_kernel(const float* __restrict__ src,
                                                   unsigned short* __restrict__ dst,
                                                   int R, int C) {
    __shared__ float tile[64][65];
    size_t eo = (size_t)blockIdx.z * R * C;
    src += eo; dst += eo;
    int tx = threadIdx.x & 15, ty = threadIdx.x >> 4;
    int c0 = blockIdx.x * 64, r0 = blockIdx.y * 64;
    #pragma unroll
    for (int i = 0; i < 4; i++) {
        int row = ty + i * 16;
        float4 v = *(const float4*)&src[(size_t)(r0 + row) * C + c0 + tx * 4];
        tile[row][tx * 4 + 0] = v.x;
        tile[row][tx * 4 + 1] = v.y;
        tile[row][tx * 4 + 2] = v.z;
        tile[row][tx * 4 + 3] = v.w;
    }
    __syncthreads();
    #pragma unroll
    for (int i = 0; i < 4; i++) {
        int cc = ty + i * 16;
        int rr = tx * 4;
        ushort4 o;
        o.x = f2bf(tile[rr + 0][cc]);
        o.y = f2bf(tile[rr + 1][cc]);
        o.z = f2bf(tile[rr + 2][cc]);
        o.w = f2bf(tile[rr + 3][cc]);
        *(ushort4*)&dst[(size_t)(c0 + cc) * R + r0 + rr] = o;
    }
}

// -------- gating: logits, top-2, softmax, entropy partials + x->bf16 --------
__global__ __launch_bounds__(256) void gating_kernel(
    const float* __restrict__ xf, const float* __restrict__ wg,
    const float* __restrict__ bg, unsigned short* __restrict__ xb,
    int* __restrict__ tk_e, float* __restrict__ tk_g,
    float* __restrict__ ent_part)
{
    __shared__ float ents[4];
    int wave = threadIdx.x >> 6, lane = threadIdx.x & 63;
    int t = blockIdx.x * 4 + wave;
    const float* xr = xf + (size_t)t * D_DIM;
    unsigned short* xbr = xb + (size_t)t * D_DIM;
    float acc[8] = {0.f,0.f,0.f,0.f,0.f,0.f,0.f,0.f};
    for (int i = 0; i < 16; i++) {
        int d = lane + i * 64;
        float xv = xr[d];
        xbr[d] = f2bf(xv);
        const float4* wr = (const float4*)(wg + (size_t)d * 8);
        float4 w0 = wr[0], w1 = wr[1];
        acc[0] += xv * w0.x; acc[1] += xv * w0.y; acc[2] += xv * w0.z; acc[3] += xv * w0.w;
        acc[4] += xv * w1.x; acc[5] += xv * w1.y; acc[6] += xv * w1.z; acc[7] += xv * w1.w;
    }
    #pragma unroll
    for (int s = 1; s < 64; s <<= 1) {
        #pragma unroll
        for (int e = 0; e < 8; e++) acc[e] += __shfl_xor(acc[e], s, 64);
    }
    if (lane == 0) {
        float l[8];
        #pragma unroll
        for (int e = 0; e < 8; e++) l[e] = acc[e] + bg[e];
        int i0 = 0;
        #pragma unroll
        for (int e = 1; e < 8; e++) if (l[e] > l[i0]) i0 = e;
        int i1 = (i0 == 0) ? 1 : 0;
        #pragma unroll
        for (int e = 0; e < 8; e++) if (e != i0 && l[e] > l[i1]) i1 = e;
        float z  = expf(l[i1] - l[i0]);          // <= 1
        float p0 = 1.0f / (1.0f + z);
        float p1 = z / (1.0f + z);
        float ent = -(p0 * logf(fmaxf(p0, 1e-8f)) + p1 * logf(fmaxf(p1, 1e-8f)));
        ents[wave] = ent;
        tk_e[t * 2 + 0] = i0; tk_g[t * 2 + 0] = p0;
        tk_e[t * 2 + 1] = i1; tk_g[t * 2 + 1] = p1;
    }
    __syncthreads();
    if (threadIdx.x == 0)
        ent_part[blockIdx.x] = ents[0] + ents[1] + ents[2] + ents[3];
}

// ------- routing: count + 256-padded offsets + scatter + entropy reduce -------
__global__ __launch_bounds__(1024) void route_kernel(
    const int* __restrict__ tk_e, const float* __restrict__ tk_g,
    int* __restrict__ off, int* __restrict__ slot_token,
    float* __restrict__ slot_gate, int* __restrict__ slot_of,
    const float* __restrict__ ent_part, float* __restrict__ ent_out)
{
    __shared__ int wt[16][8];     // per-wave totals
    __shared__ int wx[16][8];     // per-wave exclusive prefix
    __shared__ int base[9];       // padded offsets
    __shared__ int tot[8];        // true counts
    __shared__ float es[16];

    int tid = threadIdx.x, wid = tid >> 6, lane = tid & 63;
    int i0 = tid * 8;
    int ev[8];
    *(int4*)&ev[0] = *(const int4*)&tk_e[i0];
    *(int4*)&ev[4] = *(const int4*)&tk_e[i0 + 4];

    float s = ent_part[tid];
    #pragma unroll
    for (int d = 1; d < 64; d <<= 1) s += __shfl_xor(s, d, 64);
    if (lane == 0) es[wid] = s;

    unsigned own[4] = {0u, 0u, 0u, 0u};
    #pragma unroll
    for (int j = 0; j < 8; j++) {
        int e = ev[j];
        int reg = ((e < 4) ? 0 : 2) + (e & 1);
        own[reg] += 1u << (((e >> 1) & 1) * 16);
    }
    unsigned inc[4] = {own[0], own[1], own[2], own[3]};
    #pragma unroll
    for (int d = 1; d < 64; d <<= 1) {
        #pragma unroll
        for (int k = 0; k < 4; k++) {
            unsigned t = __shfl_up(inc[k], d, 64);
            if (lane >= d) inc[k] += t;
        }
    }
    if (lane == 63) {
        #pragma unroll
        for (int e = 0; e < 8; e++) {
            int reg = ((e < 4) ? 0 : 2) + (e & 1);
            wt[wid][e] = (inc[reg] >> (((e >> 1) & 1) * 16)) & 0xFFFF;
        }
    }
    __syncthreads();
    if (tid == 0) {
        int o = 0;
        for (int e = 0; e < 8; e++) {
            int run = 0;
            for (int w = 0; w < 16; w++) { wx[w][e] = run; run += wt[w][e]; }
            tot[e] = run;
            base[e] = o;
            off[e] = o;
            o += (run + 255) & ~255;     // pad to BM=256
        }
        base[8] = o;
        off[8] = o;
        float se = 0.f;
        for (int w = 0; w < 16; w++) se += es[w];
        *ent_out = se * (1.0f / T_TOK);
    }
    __syncthreads();

    #pragma unroll
    for (int e = 0; e < 8; e++) {
        int p0 = base[e] + tot[e], p1 = base[e + 1];
        for (int i = p0 + tid; i < p1; i += 1024) slot_token[i] = -1;
    }

    unsigned run[4] = {0u, 0u, 0u, 0u};
    #pragma unroll
    for (int j = 0; j < 8; j++) {
        int e = ev[j];
        int reg = ((e < 4) ? 0 : 2) + (e & 1);
        int sh = ((e >> 1) & 1) * 16;
        int lx = (int)(((inc[reg] - own[reg]) >> sh) & 0xFFFF);
        int lr = (int)((run[reg] >> sh) & 0xFFFF);
        int slot = base[e] + wx[wid][e] + lx + lr;
        run[reg] += 1u << sh;
        int i = i0 + j;
        slot_token[slot] = i >> 1;
        slot_gate[slot] = tk_g[i];
        slot_of[i] = slot;
    }
}

// ---------------- 256x256 8-phase GEMM (m201 template, MoE-grouped) ----------------
// BM=BN=256, BK=64, 512 thr = 8 waves (2M x 4N), per-wave 128x64 out (acc[8][4]).
// LDS 128KB: As[2][256x64] + Bs[2][256x64]. Per tile tt (buf b=tt&1), 4 phases:
//  ph1: LDA(q0) 8 + LDB(n01) 4 ds_reads | stage tt+1:A-half0 -> buf b^1 | bar | 16 MFMA | bar
//  ph2: LDB(n23) 4                      | stage tt+1:A-half1 -> buf b^1 | bar | 16 MFMA | bar
//  ph3: LDA(q1) 8                       | stage tt+2:B-half0 -> buf b   | bar | 16 MFMA | bar
//  ph4: (regs reused)                   | stage tt+2:B-half1 -> buf b   | bar | 16 MFMA | vmcnt(4) | bar
// Freedom: A halves of a buf are last READ at ph3, next WRITTEN at the following
// tile's ph1 (after 2 barriers); B halves last read ph2, written ph3. vmcnt(4)
// keeps the 2 newest staged halves in flight across tiles (T3+T4); setprio (T5).
// Swizzle: LDS[row][c] = G[row][c ^ (row&7)] (8-short chunks), staged via
// pre-swizzled per-lane GLOBAL address, LDS dest linear (proven in r4 kernel).
template<int KD, int ND, bool GATHER, bool RELU>
__global__ __launch_bounds__(512, 2) void gemm256_kernel(
    const unsigned short* __restrict__ Ag, const unsigned short* __restrict__ Bw,
    const float* __restrict__ bias, const int* __restrict__ off,
    const int* __restrict__ slot_token, unsigned short* __restrict__ Out)
{
    constexpr int NT = KD / 64;                 // K-tiles (16 or 32)
    __shared__ __align__(16) unsigned short As[2][16384];
    __shared__ __align__(16) unsigned short Bs[2][16384];

    int s0 = blockIdx.x * 256;
    if (s0 >= off[E_EXP]) return;
    int e = 0;
    while (s0 >= off[e + 1]) e++;
    int n0 = blockIdx.y * 256;

    int tid = threadIdx.x;
    int w = tid >> 6, lane = tid & 63;
    int wm = w >> 2, wn = w & 3;                // 2M x 4N wave grid
    int lrow = lane & 15, quad = lane >> 4;

    // staging geometry: wave w stages rows [h*128 + w*16, +16) of each half,
    // as 2 gld_lds (8 rows each). Per-lane: row += lane>>3, chunk = lane&7,
    // global chunk pre-swizzled so LDS[row][c] = G[row][c ^ (row&7)].
    int gchunk = ((lane & 7) ^ (lane >> 3)) * 8;
    int rw0 = w * 16 + (lane >> 3);
    int rw1 = rw0 + 8;

    const unsigned short* aP00; const unsigned short* aP01;
    const unsigned short* aP10; const unsigned short* aP11;
    if constexpr (GATHER) {
        int t00 = slot_token[s0 + rw0];        if (t00 < 0) t00 = 0;
        int t01 = slot_token[s0 + rw1];        if (t01 < 0) t01 = 0;
        int t10 = slot_token[s0 + 128 + rw0];  if (t10 < 0) t10 = 0;
        int t11 = slot_token[s0 + 128 + rw1];  if (t11 < 0) t11 = 0;
        aP00 = Ag + (size_t)t00 * KD + gchunk;
        aP01 = Ag + (size_t)t01 * KD + gchunk;
        aP10 = Ag + (size_t)t10 * KD + gchunk;
        aP11 = Ag + (size_t)t11 * KD + gchunk;
    } else {
        aP00 = Ag + (size_t)(s0 + rw0) * KD + gchunk;
        aP01 = Ag + (size_t)(s0 + rw1) * KD + gchunk;
        aP10 = Ag + (size_t)(s0 + 128 + rw0) * KD + gchunk;
        aP11 = Ag + (size_t)(s0 + 128 + rw1) * KD + gchunk;
    }
    const unsigned short* wbp = Bw + (size_t)e * ND * KD;
    const unsigned short* bP00 = wbp + (size_t)(n0 + rw0) * KD + gchunk;
    const unsigned short* bP01 = wbp + (size_t)(n0 + rw1) * KD + gchunk;
    const unsigned short* bP10 = wbp + (size_t)(n0 + 128 + rw0) * KD + gchunk;
    const unsigned short* bP11 = wbp + (size_t)(n0 + 128 + rw1) * KD + gchunk;

#define STAGE_A(BB, H, TT)                                                     \
    { GLD_LDS16(aP##H##0 + (TT) * 64, &As[BB][((H) * 128 + w * 16) * 64]);     \
      GLD_LDS16(aP##H##1 + (TT) * 64, &As[BB][((H) * 128 + w * 16 + 8) * 64]); }
#define STAGE_B(BB, H, TT)                                                     \
    { GLD_LDS16(bP##H##0 + (TT) * 64, &Bs[BB][((H) * 128 + w * 16) * 64]);     \
      GLD_LDS16(bP##H##1 + (TT) * 64, &Bs[BB][((H) * 128 + w * 16 + 8) * 64]); }

#define LDA(B, QM, AF)                                                         \
    _Pragma("unroll") for (int i_ = 0; i_ < 4; i_++) {                         \
        int row_ = wm * 128 + ((QM) * 4 + i_) * 16 + lrow;                     \
        int sw_ = lrow & 7;                                                    \
        int rb_ = row_ * 64;                                                   \
        AF[i_][0] = *(const bf16x8*)&As[B][rb_ + ((quad    ) ^ sw_) * 8];      \
        AF[i_][1] = *(const bf16x8*)&As[B][rb_ + ((quad + 4) ^ sw_) * 8];      \
    }
#define LDB(B, QN, BF)                                                         \
    _Pragma("unroll") for (int j_ = 0; j_ < 2; j_++) {                         \
        int row_ = wn * 64 + ((QN) * 2 + j_) * 16 + lrow;                      \
        int sw_ = lrow & 7;                                                    \
        int rb_ = row_ * 64;                                                   \
        BF[j_][0] = *(const bf16x8*)&Bs[B][rb_ + ((quad    ) ^ sw_) * 8];      \
        BF[j_][1] = *(const bf16x8*)&Bs[B][rb_ + ((quad + 4) ^ sw_) * 8];      \
    }
#define MM16(AF, BF, MB, NB)                                                   \
    __builtin_amdgcn_s_setprio(1);                                             \
    _Pragma("unroll") for (int ks_ = 0; ks_ < 2; ks_++)                        \
    _Pragma("unroll") for (int i_ = 0; i_ < 4; i_++)                           \
    _Pragma("unroll") for (int j_ = 0; j_ < 2; j_++)                           \
        acc[(MB) + i_][(NB) + j_] = __builtin_amdgcn_mfma_f32_16x16x32_bf16(   \
            AF[i_][ks_], BF[j_][ks_], acc[(MB) + i_][(NB) + j_], 0, 0, 0);     \
    __builtin_amdgcn_s_setprio(0);
#define BAR asm volatile("s_barrier" ::: "memory")

#define DO_TILE(B, SA0, SA1, SB0, SB1, GATE)                                   \
    {                                                                          \
        bf16x8 af[4][2], b01[2][2], b23[2][2];                                 \
        /* ph1: quadrant (m0, n01) */                                          \
        LDA(B, 0, af); LDB(B, 0, b01);                                         \
        SA0;                                                                   \
        BAR;                                                                   \
        MM16(af, b01, 0, 0);                                                   \
        BAR;                                                                   \
        /* ph2: quadrant (m0, n23) */                                          \
        LDB(B, 1, b23);                                                        \
        SA1;                                                                   \
        BAR;                                                                   \
        MM16(af, b23, 0, 2);                                                   \
        BAR;                                                                   \
        /* ph3: quadrant (m1, n23) */                                          \
        LDA(B, 1, af);                                                         \
        SB0;                                                                   \
        BAR;                                                                   \
        MM16(af, b23, 4, 2);                                                   \
        BAR;                                                                   \
        /* ph4: quadrant (m1, n01) */                                          \
        SB1;                                                                   \
        BAR;                                                                   \
        MM16(af, b01, 4, 0);                                                   \
        GATE;                                                                  \
        BAR;                                                                   \
    }

    f32x4 acc[8][4];
    #pragma unroll
    for (int mi = 0; mi < 8; mi++)
        #pragma unroll
        for (int ni = 0; ni < 4; ni++) acc[mi][ni] = (f32x4){0.f, 0.f, 0.f, 0.f};

    // prologue stage stream: t0:B0,B1, t0:A0,A1, t1:B0,B1 (12 loads/wave)
    STAGE_B(0, 0, 0); STAGE_B(0, 1, 0);
    STAGE_A(0, 0, 0); STAGE_A(0, 1, 0);
    STAGE_B(1, 0, 1); STAGE_B(1, 1, 1);
    asm volatile("s_waitcnt vmcnt(4)" ::: "memory");   // t0 landed; t1:B in flight
    BAR;

    for (int tt = 0; tt < NT; ++tt) {
        int b = tt & 1;
        if (tt < NT - 2) {
            DO_TILE(b,
                STAGE_A(b ^ 1, 0, tt + 1), STAGE_A(b ^ 1, 1, tt + 1),
                STAGE_B(b, 0, tt + 2),     STAGE_B(b, 1, tt + 2),
                asm volatile("s_waitcnt vmcnt(4)" ::: "memory"));
        } else if (tt == NT - 2) {
            DO_TILE(b,
                STAGE_A(b ^ 1, 0, tt + 1), STAGE_A(b ^ 1, 1, tt + 1),
                , ,
                asm volatile("s_waitcnt vmcnt(0)" ::: "memory"));
        } else {
            DO_TILE(b, , , , , );
        }
    }
#undef DO_TILE
#undef MM16
#undef LDA
#undef LDB
#undef STAGE_A
#undef STAGE_B

    // epilogue: bias(+relu) -> bf16, per-wave LDS repack -> coalesced 16B stores
    float bv[4];
    #pragma unroll
    for (int ni = 0; ni < 4; ni++)
        bv[ni] = bias[(size_t)e * ND + n0 + wn * 64 + ni * 16 + lrow];
    unsigned short* scr = &As[0][0] + w * 1024;   // 16 rows x 64 cols per wave
    #pragma unroll
    for (int mi = 0; mi < 8; mi++) {
        #pragma unroll
        for (int ni = 0; ni < 4; ni++)
            #pragma unroll
            for (int rr = 0; rr < 4; rr++) {
                float v = acc[mi][ni][rr] + bv[ni];
                if constexpr (RELU) v = fmaxf(v, 0.0f);
                scr[(quad * 4 + rr) * 64 + ni * 16 + lrow] = f2bf(v);
            }
        // intra-wave LDS dependency only: no barrier needed
        int rd = lane >> 3, cc = (lane & 7) * 8;
        bf16x8 v0 = *(const bf16x8*)&scr[rd * 64 + cc];
        bf16x8 v1 = *(const bf16x8*)&scr[(8 + rd) * 64 + cc];
        size_t rowg = (size_t)(s0 + wm * 128 + mi * 16 + rd) * ND + n0 + wn * 64 + cc;
        *(bf16x8*)&Out[rowg] = v0;
        *(bf16x8*)&Out[rowg + 8 * (size_t)ND] = v1;
    }
}

// ---------------- combine: out[t] = g0*Y[slot0] + g1*Y[slot1] ----------------
__global__ __launch_bounds__(256) void combine_kernel(
    const unsigned short* __restrict__ Yb, const int* __restrict__ slot_of,
    const float* __restrict__ tk_g, float* __restrict__ out)
{
    int t = blockIdx.x * 2 + (threadIdx.x >> 7);
    int j = threadIdx.x & 127;                 // 8 elements per thread
    int sA = slot_of[t * 2], sB = slot_of[t * 2 + 1];
    float gA = tk_g[t * 2], gB = tk_g[t * 2 + 1];
    uint4 va = *(const uint4*)(Yb + (size_t)sA * D_DIM + j * 8);
    uint4 vb = *(const uint4*)(Yb + (size_t)sB * D_DIM + j * 8);
    const unsigned int* pa = (const unsigned int*)&va;
    const unsigned int* pb = (const unsigned int*)&vb;
    float o[8];
    #pragma unroll
    for (int i = 0; i < 4; i++) {
        float a_lo = __uint_as_float(pa[i] << 16);
        float a_hi = __uint_as_float(pa[i] & 0xffff0000u);
        float b_lo = __uint_as_float(pb[i] << 16);
        float b_hi = __uint_as_float(pb[i] & 0xffff0000u);
        o[i * 2 + 0] = gA * a_lo + gB * b_lo;
        o[i * 2 + 1] = gA * a_hi + gB * b_hi;
    }
    float* op = out + (size_t)t * D_DIM + j * 8;
    ((float4*)op)[0] = make_float4(o[0], o[1], o[2], o[3]);
    ((float4*)op)[1] = make_float4(o[4], o[5], o[6], o[7]);
}

extern "C" void kernel_launch(void* const* d_in, const int* in_sizes, int n_in,
                              void* d_out, int out_size, void* d_ws, size_t ws_size,
                              hipStream_t stream)
{
    const float* xf = (const float*)d_in[0];
    const float* wg = (const float*)d_in[1];
    const float* bg = (const float*)d_in[2];
    const float* w1 = (const float*)d_in[3];
    const float* b1 = (const float*)d_in[4];
    const float* w2 = (const float*)d_in[5];
    const float* b2 = (const float*)d_in[6];
    float* out = (float*)d_out;

    char* p = (char*)d_ws;
    int* off    = (int*)p;                              // 16 (9 used)
    int* tk_e   = off + 16;                             // 8192
    float* tk_g = (float*)(tk_e + T_TOK * 2);           // 8192
    int* slot_token = (int*)(tk_g + T_TOK * 2);         // CAP
    float* slot_gate = (float*)(slot_token + CAP);      // CAP
    int* slot_of = (int*)(slot_gate + CAP);             // 8192
    float* ent_part = (float*)(slot_of + T_TOK * 2);    // 1024
    size_t ofs = ((size_t)((char*)(ent_part + T_TOK / 4) - p) + 255) & ~(size_t)255;
    unsigned short* xb  = (unsigned short*)(p + ofs); ofs += (size_t)T_TOK * D_DIM * 2;
    unsigned short* w1t = (unsigned short*)(p + ofs); ofs += (size_t)E_EXP * D_DIM * H_DIM * 2;
    unsigned short* w2t = (unsigned short*)(p + ofs); ofs += (size_t)E_EXP * H_DIM * D_DIM * 2;
    unsigned short* Hb  = (unsigned short*)(p + ofs); ofs += (size_t)CAP * H_DIM * 2;
    unsigned short* Yb  = w1t;   // alias: w1t is dead after gemm1

    gating_kernel<<<T_TOK / 4, 256, 0, stream>>>(xf, wg, bg, xb, tk_e, tk_g, ent_part);
    route_kernel<<<1, 1024, 0, stream>>>(tk_e, tk_g, off, slot_token, slot_gate, slot_of,
                                         ent_part, out + (size_t)T_TOK * D_DIM);
    // w1 (E, D, H) -> w1t (E, H, D)
    tcvt_kernel<<<dim3(H_DIM / 64, D_DIM / 64, E_EXP), 256, 0, stream>>>(w1, w1t, D_DIM, H_DIM);
    // w2 (E, H, D) -> w2t (E, D, H)
    tcvt_kernel<<<dim3(D_DIM / 64, H_DIM / 64, E_EXP), 256, 0, stream>>>(w2, w2t, H_DIM, D_DIM);
    // GEMM1: Hb = relu(gather(xb) @ w1t[e]^T + b1[e])
    gemm256_kernel<D_DIM, H_DIM, true, true>
        <<<dim3(TILES_M, H_DIM / 256), 512, 0, stream>>>(xb, w1t, b1, off, slot_token, Hb);
    // GEMM2: Yb = Hb @ w2t[e]^T + b2[e]
    gemm256_kernel<H_DIM, D_DIM, false, false>
        <<<dim3(TILES_M, D_DIM / 256), 512, 0, stream>>>(Hb, w2t, b2, off, slot_token, Yb);
    combine_kernel<<<T_TOK / 2, 256, 0, stream>>>(Yb, slot_of, tk_g, out);
}

// Round 6
// 827.487 us; speedup vs baseline: 1.0029x; 1.0029x over previous
//
#include <hip/hip_runtime.h>

#define T_TOK 4096
#define D_DIM 1024
#define E_EXP 8
#define H_DIM 2048
#define CAP   10240  // 8192 slots + 8*256 tile padding (BM=256)
#define TILES_M 40   // CAP/256

typedef __attribute__((ext_vector_type(8))) short bf16x8;
typedef __attribute__((ext_vector_type(4))) float f32x4;

__device__ inline unsigned short f2bf(float f) {
    unsigned int u = __float_as_uint(f);
    unsigned int r = (u + 0x7fffu + ((u >> 16) & 1u)) >> 16;
    return (unsigned short)r;
}

#define GLD_LDS16(g, l)                                                        \
    __builtin_amdgcn_global_load_lds(                                          \
        (const __attribute__((address_space(1))) void*)(g),                    \
        (__attribute__((address_space(3))) void*)(l), 16, 0, 0)

// ------------- fp32 (R,C) -> bf16 transposed (C,R), per expert -------------
__global__ __launch_bounds__(256) void tcvt_kernel(const float* __restrict__ src,
                                                   unsigned short* __restrict__ dst,
                                                   int R, int C) {
    __shared__ float tile[64][65];
    size_t eo = (size_t)blockIdx.z * R * C;
    src += eo; dst += eo;
    int tx = threadIdx.x & 15, ty = threadIdx.x >> 4;
    int c0 = blockIdx.x * 64, r0 = blockIdx.y * 64;
    #pragma unroll
    for (int i = 0; i < 4; i++) {
        int row = ty + i * 16;
        float4 v = *(const float4*)&src[(size_t)(r0 + row) * C + c0 + tx * 4];
        tile[row][tx * 4 + 0] = v.x;
        tile[row][tx * 4 + 1] = v.y;
        tile[row][tx * 4 + 2] = v.z;
        tile[row][tx * 4 + 3] = v.w;
    }
    __syncthreads();
    #pragma unroll
    for (int i = 0; i < 4; i++) {
        int cc = ty + i * 16;
        int rr = tx * 4;
        ushort4 o;
        o.x = f2bf(tile[rr + 0][cc]);
        o.y = f2bf(tile[rr + 1][cc]);
        o.z = f2bf(tile[rr + 2][cc]);
        o.w = f2bf(tile[rr + 3][cc]);
        *(ushort4*)&dst[(size_t)(c0 + cc) * R + r0 + rr] = o;
    }
}

// -------- gating: logits, top-2, softmax, entropy partials + x->bf16 --------
__global__ __launch_bounds__(256) void gating_kernel(
    const float* __restrict__ xf, const float* __restrict__ wg,
    const float* __restrict__ bg, unsigned short* __restrict__ xb,
    int* __restrict__ tk_e, float* __restrict__ tk_g,
    float* __restrict__ ent_part)
{
    __shared__ float ents[4];
    int wave = threadIdx.x >> 6, lane = threadIdx.x & 63;
    int t = blockIdx.x * 4 + wave;
    const float* xr = xf + (size_t)t * D_DIM;
    unsigned short* xbr = xb + (size_t)t * D_DIM;
    float acc[8] = {0.f,0.f,0.f,0.f,0.f,0.f,0.f,0.f};
    for (int i = 0; i < 16; i++) {
        int d = lane + i * 64;
        float xv = xr[d];
        xbr[d] = f2bf(xv);
        const float4* wr = (const float4*)(wg + (size_t)d * 8);
        float4 w0 = wr[0], w1 = wr[1];
        acc[0] += xv * w0.x; acc[1] += xv * w0.y; acc[2] += xv * w0.z; acc[3] += xv * w0.w;
        acc[4] += xv * w1.x; acc[5] += xv * w1.y; acc[6] += xv * w1.z; acc[7] += xv * w1.w;
    }
    #pragma unroll
    for (int s = 1; s < 64; s <<= 1) {
        #pragma unroll
        for (int e = 0; e < 8; e++) acc[e] += __shfl_xor(acc[e], s, 64);
    }
    if (lane == 0) {
        float l[8];
        #pragma unroll
        for (int e = 0; e < 8; e++) l[e] = acc[e] + bg[e];
        int i0 = 0;
        #pragma unroll
        for (int e = 1; e < 8; e++) if (l[e] > l[i0]) i0 = e;
        int i1 = (i0 == 0) ? 1 : 0;
        #pragma unroll
        for (int e = 0; e < 8; e++) if (e != i0 && l[e] > l[i1]) i1 = e;
        float z  = expf(l[i1] - l[i0]);          // <= 1
        float p0 = 1.0f / (1.0f + z);
        float p1 = z / (1.0f + z);
        float ent = -(p0 * logf(fmaxf(p0, 1e-8f)) + p1 * logf(fmaxf(p1, 1e-8f)));
        ents[wave] = ent;
        tk_e[t * 2 + 0] = i0; tk_g[t * 2 + 0] = p0;
        tk_e[t * 2 + 1] = i1; tk_g[t * 2 + 1] = p1;
    }
    __syncthreads();
    if (threadIdx.x == 0)
        ent_part[blockIdx.x] = ents[0] + ents[1] + ents[2] + ents[3];
}

// ------- routing: count + 256-padded offsets + scatter + entropy reduce -------
__global__ __launch_bounds__(1024) void route_kernel(
    const int* __restrict__ tk_e, const float* __restrict__ tk_g,
    int* __restrict__ off, int* __restrict__ slot_token,
    float* __restrict__ slot_gate, int* __restrict__ slot_of,
    const float* __restrict__ ent_part, float* __restrict__ ent_out)
{
    __shared__ int wt[16][8];     // per-wave totals
    __shared__ int wx[16][8];     // per-wave exclusive prefix
    __shared__ int base[9];       // padded offsets
    __shared__ int tot[8];        // true counts
    __shared__ float es[16];

    int tid = threadIdx.x, wid = tid >> 6, lane = tid & 63;
    int i0 = tid * 8;
    int ev[8];
    *(int4*)&ev[0] = *(const int4*)&tk_e[i0];
    *(int4*)&ev[4] = *(const int4*)&tk_e[i0 + 4];

    float s = ent_part[tid];
    #pragma unroll
    for (int d = 1; d < 64; d <<= 1) s += __shfl_xor(s, d, 64);
    if (lane == 0) es[wid] = s;

    unsigned own[4] = {0u, 0u, 0u, 0u};
    #pragma unroll
    for (int j = 0; j < 8; j++) {
        int e = ev[j];
        int reg = ((e < 4) ? 0 : 2) + (e & 1);
        own[reg] += 1u << (((e >> 1) & 1) * 16);
    }
    unsigned inc[4] = {own[0], own[1], own[2], own[3]};
    #pragma unroll
    for (int d = 1; d < 64; d <<= 1) {
        #pragma unroll
        for (int k = 0; k < 4; k++) {
            unsigned t = __shfl_up(inc[k], d, 64);
            if (lane >= d) inc[k] += t;
        }
    }
    if (lane == 63) {
        #pragma unroll
        for (int e = 0; e < 8; e++) {
            int reg = ((e < 4) ? 0 : 2) + (e & 1);
            wt[wid][e] = (inc[reg] >> (((e >> 1) & 1) * 16)) & 0xFFFF;
        }
    }
    __syncthreads();
    if (tid == 0) {
        int o = 0;
        for (int e = 0; e < 8; e++) {
            int run = 0;
            for (int w = 0; w < 16; w++) { wx[w][e] = run; run += wt[w][e]; }
            tot[e] = run;
            base[e] = o;
            off[e] = o;
            o += (run + 255) & ~255;     // pad to BM=256
        }
        base[8] = o;
        off[8] = o;
        float se = 0.f;
        for (int w = 0; w < 16; w++) se += es[w];
        *ent_out = se * (1.0f / T_TOK);
    }
    __syncthreads();

    #pragma unroll
    for (int e = 0; e < 8; e++) {
        int p0 = base[e] + tot[e], p1 = base[e + 1];
        for (int i = p0 + tid; i < p1; i += 1024) slot_token[i] = -1;
    }

    unsigned run[4] = {0u, 0u, 0u, 0u};
    #pragma unroll
    for (int j = 0; j < 8; j++) {
        int e = ev[j];
        int reg = ((e < 4) ? 0 : 2) + (e & 1);
        int sh = ((e >> 1) & 1) * 16;
        int lx = (int)(((inc[reg] - own[reg]) >> sh) & 0xFFFF);
        int lr = (int)((run[reg] >> sh) & 0xFFFF);
        int slot = base[e] + wx[wid][e] + lx + lr;
        run[reg] += 1u << sh;
        int i = i0 + j;
        slot_token[slot] = i >> 1;
        slot_gate[slot] = tk_g[i];
        slot_of[i] = slot;
    }
}

// ---------------- 256x256 8-phase GEMM (m201 template, MoE-grouped) ----------------
// BM=BN=256, BK=64, 512 thr = 8 waves (2M x 4N), per-wave 128x64 out (acc[8][4]).
// LDS 128KB: As[2][256x64] + Bs[2][256x64]. Per tile tt (buf b=tt&1), 4 phases:
//  ph1: LDA(q0) 8 + LDB(n01) 4 ds_reads | stage tt+1:A-half0 -> buf b^1 | bar | 16 MFMA | bar
//  ph2: LDB(n23) 4                      | stage tt+1:A-half1 -> buf b^1 | bar | 16 MFMA | bar
//  ph3: LDA(q1) 8                       | stage tt+2:B-half0 -> buf b   | bar | 16 MFMA | bar
//  ph4: (regs reused)                   | stage tt+2:B-half1 -> buf b   | bar | 16 MFMA | vmcnt(4) | bar
// vmcnt(4) keeps the 2 newest staged halves in flight across tiles (T3+T4);
// setprio around MFMA clusters (T5). Swizzle: LDS[row][c] = G[row][c ^ (row&7)],
// staged via pre-swizzled per-lane GLOBAL address, LDS dest linear.
// __launch_bounds__(512, 1): REGISTER FIX vs r5 — (512,2) capped unified
// VGPR+AGPR at 256/wave; acc[8][4]=128 AGPR + temps overflowed -> scratch
// thrash (WRITE_SIZE 392MB, MfmaUtil 4.5%). Cap 512 removes the spills.
template<int KD, int ND, bool GATHER, bool RELU>
__global__ __launch_bounds__(512, 1) void gemm256_kernel(
    const unsigned short* __restrict__ Ag, const unsigned short* __restrict__ Bw,
    const float* __restrict__ bias, const int* __restrict__ off,
    const int* __restrict__ slot_token, unsigned short* __restrict__ Out)
{
    constexpr int NT = KD / 64;                 // K-tiles (16 or 32)
    __shared__ __align__(16) unsigned short As[2][16384];
    __shared__ __align__(16) unsigned short Bs[2][16384];

    int s0 = blockIdx.x * 256;
    if (s0 >= off[E_EXP]) return;
    int e = 0;
    while (s0 >= off[e + 1]) e++;
    int n0 = blockIdx.y * 256;

    int tid = threadIdx.x;
    int w = tid >> 6, lane = tid & 63;
    int wm = w >> 2, wn = w & 3;                // 2M x 4N wave grid
    int lrow = lane & 15, quad = lane >> 4;

    // staging geometry: wave w stages rows [h*128 + w*16, +16) of each half,
    // as 2 gld_lds (8 rows each). Per-lane: row += lane>>3, chunk = lane&7,
    // global chunk pre-swizzled so LDS[row][c] = G[row][c ^ (row&7)].
    int gchunk = ((lane & 7) ^ (lane >> 3)) * 8;
    int rw0 = w * 16 + (lane >> 3);
    int rw1 = rw0 + 8;

    const unsigned short* aP00; const unsigned short* aP01;
    const unsigned short* aP10; const unsigned short* aP11;
    if constexpr (GATHER) {
        int t00 = slot_token[s0 + rw0];        if (t00 < 0) t00 = 0;
        int t01 = slot_token[s0 + rw1];        if (t01 < 0) t01 = 0;
        int t10 = slot_token[s0 + 128 + rw0];  if (t10 < 0) t10 = 0;
        int t11 = slot_token[s0 + 128 + rw1];  if (t11 < 0) t11 = 0;
        aP00 = Ag + (size_t)t00 * KD + gchunk;
        aP01 = Ag + (size_t)t01 * KD + gchunk;
        aP10 = Ag + (size_t)t10 * KD + gchunk;
        aP11 = Ag + (size_t)t11 * KD + gchunk;
    } else {
        aP00 = Ag + (size_t)(s0 + rw0) * KD + gchunk;
        aP01 = Ag + (size_t)(s0 + rw1) * KD + gchunk;
        aP10 = Ag + (size_t)(s0 + 128 + rw0) * KD + gchunk;
        aP11 = Ag + (size_t)(s0 + 128 + rw1) * KD + gchunk;
    }
    const unsigned short* wbp = Bw + (size_t)e * ND * KD;
    const unsigned short* bP00 = wbp + (size_t)(n0 + rw0) * KD + gchunk;
    const unsigned short* bP01 = wbp + (size_t)(n0 + rw1) * KD + gchunk;
    const unsigned short* bP10 = wbp + (size_t)(n0 + 128 + rw0) * KD + gchunk;
    const unsigned short* bP11 = wbp + (size_t)(n0 + 128 + rw1) * KD + gchunk;

#define STAGE_A(BB, H, TT)                                                     \
    { GLD_LDS16(aP##H##0 + (TT) * 64, &As[BB][((H) * 128 + w * 16) * 64]);     \
      GLD_LDS16(aP##H##1 + (TT) * 64, &As[BB][((H) * 128 + w * 16 + 8) * 64]); }
#define STAGE_B(BB, H, TT)                                                     \
    { GLD_LDS16(bP##H##0 + (TT) * 64, &Bs[BB][((H) * 128 + w * 16) * 64]);     \
      GLD_LDS16(bP##H##1 + (TT) * 64, &Bs[BB][((H) * 128 + w * 16 + 8) * 64]); }

#define LDA(B, QM, AF)                                                         \
    _Pragma("unroll") for (int i_ = 0; i_ < 4; i_++) {                         \
        int row_ = wm * 128 + ((QM) * 4 + i_) * 16 + lrow;                     \
        int sw_ = lrow & 7;                                                    \
        int rb_ = row_ * 64;                                                   \
        AF[i_][0] = *(const bf16x8*)&As[B][rb_ + ((quad    ) ^ sw_) * 8];      \
        AF[i_][1] = *(const bf16x8*)&As[B][rb_ + ((quad + 4) ^ sw_) * 8];      \
    }
#define LDB(B, QN, BF)                                                         \
    _Pragma("unroll") for (int j_ = 0; j_ < 2; j_++) {                         \
        int row_ = wn * 64 + ((QN) * 2 + j_) * 16 + lrow;                      \
        int sw_ = lrow & 7;                                                    \
        int rb_ = row_ * 64;                                                   \
        BF[j_][0] = *(const bf16x8*)&Bs[B][rb_ + ((quad    ) ^ sw_) * 8];      \
        BF[j_][1] = *(const bf16x8*)&Bs[B][rb_ + ((quad + 4) ^ sw_) * 8];      \
    }
#define MM16(AF, BF, MB, NB)                                                   \
    __builtin_amdgcn_s_setprio(1);                                             \
    _Pragma("unroll") for (int ks_ = 0; ks_ < 2; ks_++)                        \
    _Pragma("unroll") for (int i_ = 0; i_ < 4; i_++)                           \
    _Pragma("unroll") for (int j_ = 0; j_ < 2; j_++)                           \
        acc[(MB) + i_][(NB) + j_] = __builtin_amdgcn_mfma_f32_16x16x32_bf16(   \
            AF[i_][ks_], BF[j_][ks_], acc[(MB) + i_][(NB) + j_], 0, 0, 0);     \
    __builtin_amdgcn_s_setprio(0);
#define BAR asm volatile("s_barrier" ::: "memory")

#define DO_TILE(B, SA0, SA1, SB0, SB1, GATE)                                   \
    {                                                                          \
        bf16x8 af[4][2], b01[2][2], b23[2][2];                                 \
        /* ph1: quadrant (m0, n01) */                                          \
        LDA(B, 0, af); LDB(B, 0, b01);                                         \
        SA0;                                                                   \
        BAR;                                                                   \
        MM16(af, b01, 0, 0);                                                   \
        BAR;                                                                   \
        /* ph2: quadrant (m0, n23) */                                          \
        LDB(B, 1, b23);                                                        \
        SA1;                                                                   \
        BAR;                                                                   \
        MM16(af, b23, 0, 2);                                                   \
        BAR;                                                                   \
        /* ph3: quadrant (m1, n23) */                                          \
        LDA(B, 1, af);                                                         \
        SB0;                                                                   \
        BAR;                                                                   \
        MM16(af, b23, 4, 2);                                                   \
        BAR;                                                                   \
        /* ph4: quadrant (m1, n01) */                                          \
        SB1;                                                                   \
        BAR;                                                                   \
        MM16(af, b01, 4, 0);                                                   \
        GATE;                                                                  \
        BAR;                                                                   \
    }

    f32x4 acc[8][4];
    #pragma unroll
    for (int mi = 0; mi < 8; mi++)
        #pragma unroll
        for (int ni = 0; ni < 4; ni++) acc[mi][ni] = (f32x4){0.f, 0.f, 0.f, 0.f};

    // prologue stage stream: t0:B0,B1, t0:A0,A1, t1:B0,B1 (12 loads/wave)
    STAGE_B(0, 0, 0); STAGE_B(0, 1, 0);
    STAGE_A(0, 0, 0); STAGE_A(0, 1, 0);
    STAGE_B(1, 0, 1); STAGE_B(1, 1, 1);
    asm volatile("s_waitcnt vmcnt(4)" ::: "memory");   // t0 landed; t1:B in flight
    BAR;

    for (int tt = 0; tt < NT; ++tt) {
        int b = tt & 1;
        if (tt < NT - 2) {
            DO_TILE(b,
                STAGE_A(b ^ 1, 0, tt + 1), STAGE_A(b ^ 1, 1, tt + 1),
                STAGE_B(b, 0, tt + 2),     STAGE_B(b, 1, tt + 2),
                asm volatile("s_waitcnt vmcnt(4)" ::: "memory"));
        } else if (tt == NT - 2) {
            DO_TILE(b,
                STAGE_A(b ^ 1, 0, tt + 1), STAGE_A(b ^ 1, 1, tt + 1),
                , ,
                asm volatile("s_waitcnt vmcnt(0)" ::: "memory"));
        } else {
            DO_TILE(b, , , , , );
        }
    }
#undef DO_TILE
#undef MM16
#undef LDA
#undef LDB
#undef STAGE_A
#undef STAGE_B

    // epilogue: bias(+relu) -> bf16, per-wave LDS repack -> coalesced 16B stores
    float bv[4];
    #pragma unroll
    for (int ni = 0; ni < 4; ni++)
        bv[ni] = bias[(size_t)e * ND + n0 + wn * 64 + ni * 16 + lrow];
    unsigned short* scr = &As[0][0] + w * 1024;   // 16 rows x 64 cols per wave
    #pragma unroll
    for (int mi = 0; mi < 8; mi++) {
        #pragma unroll
        for (int ni = 0; ni < 4; ni++)
            #pragma unroll
            for (int rr = 0; rr < 4; rr++) {
                float v = acc[mi][ni][rr] + bv[ni];
                if constexpr (RELU) v = fmaxf(v, 0.0f);
                scr[(quad * 4 + rr) * 64 + ni * 16 + lrow] = f2bf(v);
            }
        // intra-wave LDS dependency only: no barrier needed
        int rd = lane >> 3, cc = (lane & 7) * 8;
        bf16x8 v0 = *(const bf16x8*)&scr[rd * 64 + cc];
        bf16x8 v1 = *(const bf16x8*)&scr[(8 + rd) * 64 + cc];
        size_t rowg = (size_t)(s0 + wm * 128 + mi * 16 + rd) * ND + n0 + wn * 64 + cc;
        *(bf16x8*)&Out[rowg] = v0;
        *(bf16x8*)&Out[rowg + 8 * (size_t)ND] = v1;
    }
}

// ---------------- combine: out[t] = g0*Y[slot0] + g1*Y[slot1] ----------------
__global__ __launch_bounds__(256) void combine_kernel(
    const unsigned short* __restrict__ Yb, const int* __restrict__ slot_of,
    const float* __restrict__ tk_g, float* __restrict__ out)
{
    int t = blockIdx.x * 2 + (threadIdx.x >> 7);
    int j = threadIdx.x & 127;                 // 8 elements per thread
    int sA = slot_of[t * 2], sB = slot_of[t * 2 + 1];
    float gA = tk_g[t * 2], gB = tk_g[t * 2 + 1];
    uint4 va = *(const uint4*)(Yb + (size_t)sA * D_DIM + j * 8);
    uint4 vb = *(const uint4*)(Yb + (size_t)sB * D_DIM + j * 8);
    const unsigned int* pa = (const unsigned int*)&va;
    const unsigned int* pb = (const unsigned int*)&vb;
    float o[8];
    #pragma unroll
    for (int i = 0; i < 4; i++) {
        float a_lo = __uint_as_float(pa[i] << 16);
        float a_hi = __uint_as_float(pa[i] & 0xffff0000u);
        float b_lo = __uint_as_float(pb[i] << 16);
        float b_hi = __uint_as_float(pb[i] & 0xffff0000u);
        o[i * 2 + 0] = gA * a_lo + gB * b_lo;
        o[i * 2 + 1] = gA * a_hi + gB * b_hi;
    }
    float* op = out + (size_t)t * D_DIM + j * 8;
    ((float4*)op)[0] = make_float4(o[0], o[1], o[2], o[3]);
    ((float4*)op)[1] = make_float4(o[4], o[5], o[6], o[7]);
}

extern "C" void kernel_launch(void* const* d_in, const int* in_sizes, int n_in,
                              void* d_out, int out_size, void* d_ws, size_t ws_size,
                              hipStream_t stream)
{
    const float* xf = (const float*)d_in[0];
    const float* wg = (const float*)d_in[1];
    const float* bg = (const float*)d_in[2];
    const float* w1 = (const float*)d_in[3];
    const float* b1 = (const float*)d_in[4];
    const float* w2 = (const float*)d_in[5];
    const float* b2 = (const float*)d_in[6];
    float* out = (float*)d_out;

    char* p = (char*)d_ws;
    int* off    = (int*)p;                              // 16 (9 used)
    int* tk_e   = off + 16;                             // 8192
    float* tk_g = (float*)(tk_e + T_TOK * 2);           // 8192
    int* slot_token = (int*)(tk_g + T_TOK * 2);         // CAP
    float* slot_gate = (float*)(slot_token + CAP);      // CAP
    int* slot_of = (int*)(slot_gate + CAP);             // 8192
    float* ent_part = (float*)(slot_of + T_TOK * 2);    // 1024
    size_t ofs = ((size_t)((char*)(ent_part + T_TOK / 4) - p) + 255) & ~(size_t)255;
    unsigned short* xb  = (unsigned short*)(p + ofs); ofs += (size_t)T_TOK * D_DIM * 2;
    unsigned short* w1t = (unsigned short*)(p + ofs); ofs += (size_t)E_EXP * D_DIM * H_DIM * 2;
    unsigned short* w2t = (unsigned short*)(p + ofs); ofs += (size_t)E_EXP * H_DIM * D_DIM * 2;
    unsigned short* Hb  = (unsigned short*)(p + ofs); ofs += (size_t)CAP * H_DIM * 2;
    unsigned short* Yb  = w1t;   // alias: w1t is dead after gemm1

    gating_kernel<<<T_TOK / 4, 256, 0, stream>>>(xf, wg, bg, xb, tk_e, tk_g, ent_part);
    route_kernel<<<1, 1024, 0, stream>>>(tk_e, tk_g, off, slot_token, slot_gate, slot_of,
                                         ent_part, out + (size_t)T_TOK * D_DIM);
    // w1 (E, D, H) -> w1t (E, H, D)
    tcvt_kernel<<<dim3(H_DIM / 64, D_DIM / 64, E_EXP), 256, 0, stream>>>(w1, w1t, D_DIM, H_DIM);
    // w2 (E, H, D) -> w2t (E, D, H)
    tcvt_kernel<<<dim3(D_DIM / 64, H_DIM / 64, E_EXP), 256, 0, stream>>>(w2, w2t, H_DIM, D_DIM);
    // GEMM1: Hb = relu(gather(xb) @ w1t[e]^T + b1[e])
    gemm256_kernel<D_DIM, H_DIM, true, true>
        <<<dim3(TILES_M, H_DIM / 256), 512, 0, stream>>>(xb, w1t, b1, off, slot_token, Hb);
    // GEMM2: Yb = Hb @ w2t[e]^T + b2[e]
    gemm256_kernel<H_DIM, D_DIM, false, false>
        <<<dim3(TILES_M, D_DIM / 256), 512, 0, stream>>>(Hb, w2t, b2, off, slot_token, Yb);
    combine_kernel<<<T_TOK / 2, 256, 0, stream>>>(Yb, slot_of, tk_g, out);
}

// Round 7
// 331.408 us; speedup vs baseline: 2.5042x; 2.4969x over previous
//
#include <hip/hip_runtime.h>

#define T_TOK 4096
#define D_DIM 1024
#define E_EXP 8
#define H_DIM 2048
#define CAP   9216   // 8192 slots + 8*128 tile padding
#define TILES_M 72   // CAP/128

typedef __attribute__((ext_vector_type(8))) short bf16x8;
typedef __attribute__((ext_vector_type(4))) float f32x4;

__device__ inline unsigned short f2bf(float f) {
    unsigned int u = __float_as_uint(f);
    unsigned int r = (u + 0x7fffu + ((u >> 16) & 1u)) >> 16;
    return (unsigned short)r;
}

#define GLD_LDS16(g, l)                                                        \
    __builtin_amdgcn_global_load_lds(                                          \
        (const __attribute__((address_space(1))) void*)(g),                    \
        (__attribute__((address_space(3))) void*)(l), 16, 0, 0)

// ------------- fp32 (R,C) -> bf16 transposed (C,R), per expert -------------
__global__ __launch_bounds__(256) void tcvt_kernel(const float* __restrict__ src,
                                                   unsigned short* __restrict__ dst,
                                                   int R, int C) {
    __shared__ float tile[64][65];
    size_t eo = (size_t)blockIdx.z * R * C;
    src += eo; dst += eo;
    int tx = threadIdx.x & 15, ty = threadIdx.x >> 4;
    int c0 = blockIdx.x * 64, r0 = blockIdx.y * 64;
    #pragma unroll
    for (int i = 0; i < 4; i++) {
        int row = ty + i * 16;
        float4 v = *(const float4*)&src[(size_t)(r0 + row) * C + c0 + tx * 4];
        tile[row][tx * 4 + 0] = v.x;
        tile[row][tx * 4 + 1] = v.y;
        tile[row][tx * 4 + 2] = v.z;
        tile[row][tx * 4 + 3] = v.w;
    }
    __syncthreads();
    #pragma unroll
    for (int i = 0; i < 4; i++) {
        int cc = ty + i * 16;
        int rr = tx * 4;
        ushort4 o;
        o.x = f2bf(tile[rr + 0][cc]);
        o.y = f2bf(tile[rr + 1][cc]);
        o.z = f2bf(tile[rr + 2][cc]);
        o.w = f2bf(tile[rr + 3][cc]);
        *(ushort4*)&dst[(size_t)(c0 + cc) * R + r0 + rr] = o;
    }
}

// -------- gating: logits, top-2, softmax, entropy partials + x->bf16 --------
__global__ __launch_bounds__(256) void gating_kernel(
    const float* __restrict__ xf, const float* __restrict__ wg,
    const float* __restrict__ bg, unsigned short* __restrict__ xb,
    int* __restrict__ tk_e, float* __restrict__ tk_g,
    float* __restrict__ ent_part)
{
    __shared__ float ents[4];
    int wave = threadIdx.x >> 6, lane = threadIdx.x & 63;
    int t = blockIdx.x * 4 + wave;
    const float* xr = xf + (size_t)t * D_DIM;
    unsigned short* xbr = xb + (size_t)t * D_DIM;
    float acc[8] = {0.f,0.f,0.f,0.f,0.f,0.f,0.f,0.f};
    for (int i = 0; i < 16; i++) {
        int d = lane + i * 64;
        float xv = xr[d];
        xbr[d] = f2bf(xv);
        const float4* wr = (const float4*)(wg + (size_t)d * 8);
        float4 w0 = wr[0], w1 = wr[1];
        acc[0] += xv * w0.x; acc[1] += xv * w0.y; acc[2] += xv * w0.z; acc[3] += xv * w0.w;
        acc[4] += xv * w1.x; acc[5] += xv * w1.y; acc[6] += xv * w1.z; acc[7] += xv * w1.w;
    }
    #pragma unroll
    for (int s = 1; s < 64; s <<= 1) {
        #pragma unroll
        for (int e = 0; e < 8; e++) acc[e] += __shfl_xor(acc[e], s, 64);
    }
    if (lane == 0) {
        float l[8];
        #pragma unroll
        for (int e = 0; e < 8; e++) l[e] = acc[e] + bg[e];
        int i0 = 0;
        #pragma unroll
        for (int e = 1; e < 8; e++) if (l[e] > l[i0]) i0 = e;
        int i1 = (i0 == 0) ? 1 : 0;
        #pragma unroll
        for (int e = 0; e < 8; e++) if (e != i0 && l[e] > l[i1]) i1 = e;
        float z  = expf(l[i1] - l[i0]);          // <= 1
        float p0 = 1.0f / (1.0f + z);
        float p1 = z / (1.0f + z);
        float ent = -(p0 * logf(fmaxf(p0, 1e-8f)) + p1 * logf(fmaxf(p1, 1e-8f)));
        ents[wave] = ent;
        tk_e[t * 2 + 0] = i0; tk_g[t * 2 + 0] = p0;
        tk_e[t * 2 + 1] = i1; tk_g[t * 2 + 1] = p1;
    }
    __syncthreads();
    if (threadIdx.x == 0)
        ent_part[blockIdx.x] = ents[0] + ents[1] + ents[2] + ents[3];
}

// ------- routing: count + padded offsets + scatter + entropy reduce -------
__global__ __launch_bounds__(1024) void route_kernel(
    const int* __restrict__ tk_e, const float* __restrict__ tk_g,
    int* __restrict__ off, int* __restrict__ slot_token,
    float* __restrict__ slot_gate, int* __restrict__ slot_of,
    const float* __restrict__ ent_part, float* __restrict__ ent_out)
{
    __shared__ int wt[16][8];     // per-wave totals
    __shared__ int wx[16][8];     // per-wave exclusive prefix
    __shared__ int base[9];       // padded offsets
    __shared__ int tot[8];        // true counts
    __shared__ float es[16];

    int tid = threadIdx.x, wid = tid >> 6, lane = tid & 63;
    int i0 = tid * 8;
    int ev[8];
    *(int4*)&ev[0] = *(const int4*)&tk_e[i0];
    *(int4*)&ev[4] = *(const int4*)&tk_e[i0 + 4];

    float s = ent_part[tid];
    #pragma unroll
    for (int d = 1; d < 64; d <<= 1) s += __shfl_xor(s, d, 64);
    if (lane == 0) es[wid] = s;

    unsigned own[4] = {0u, 0u, 0u, 0u};
    #pragma unroll
    for (int j = 0; j < 8; j++) {
        int e = ev[j];
        int reg = ((e < 4) ? 0 : 2) + (e & 1);
        own[reg] += 1u << (((e >> 1) & 1) * 16);
    }
    unsigned inc[4] = {own[0], own[1], own[2], own[3]};
    #pragma unroll
    for (int d = 1; d < 64; d <<= 1) {
        #pragma unroll
        for (int k = 0; k < 4; k++) {
            unsigned t = __shfl_up(inc[k], d, 64);
            if (lane >= d) inc[k] += t;
        }
    }
    if (lane == 63) {
        #pragma unroll
        for (int e = 0; e < 8; e++) {
            int reg = ((e < 4) ? 0 : 2) + (e & 1);
            wt[wid][e] = (inc[reg] >> (((e >> 1) & 1) * 16)) & 0xFFFF;
        }
    }
    __syncthreads();
    if (tid == 0) {
        int o = 0;
        for (int e = 0; e < 8; e++) {
            int run = 0;
            for (int w = 0; w < 16; w++) { wx[w][e] = run; run += wt[w][e]; }
            tot[e] = run;
            base[e] = o;
            off[e] = o;
            o += (run + 127) & ~127;
        }
        base[8] = o;
        off[8] = o;
        float se = 0.f;
        for (int w = 0; w < 16; w++) se += es[w];
        *ent_out = se * (1.0f / T_TOK);
    }
    __syncthreads();

    #pragma unroll
    for (int e = 0; e < 8; e++) {
        int p0 = base[e] + tot[e], p1 = base[e + 1];
        for (int i = p0 + tid; i < p1; i += 1024) slot_token[i] = -1;
    }

    unsigned run[4] = {0u, 0u, 0u, 0u};
    #pragma unroll
    for (int j = 0; j < 8; j++) {
        int e = ev[j];
        int reg = ((e < 4) ? 0 : 2) + (e & 1);
        int sh = ((e >> 1) & 1) * 16;
        int lx = (int)(((inc[reg] - own[reg]) >> sh) & 0xFFFF);
        int lr = (int)((run[reg] >> sh) & 0xFFFF);
        int slot = base[e] + wx[wid][e] + lx + lr;
        run[reg] += 1u << sh;
        int i = i0 + j;
        slot_token[slot] = i >> 1;
        slot_gate[slot] = tk_g[i];
        slot_of[i] = slot;
    }
}

// -------- GEMM: round-0 geometry (128x128, BK=32, 32KB LDS, 4 waves) --------
// ONE change vs round-0: the per-K-step sync is counted-vmcnt + raw s_barrier
// instead of __syncthreads (which drains vmcnt(0) and exposes the full staging
// latency every step). Double-buffered; prologue keeps steps 0,1 in flight
// (8 loads); per step: vmcnt(4) [step t landed, t+1 still in flight] -> bar ->
// 8 ds_read + 16 MFMA/wave (setprio) -> bar -> stage step t+2 into freed buf.
// vmcnt reaches 0 only in the peeled final step. Staging layout, swizzle,
// fragment reads, and epilogue are byte-identical to the verified round-0.
template<int KD, int ND, bool GATHER, bool RELU>
__global__ __launch_bounds__(256) void gemm_kernel(
    const unsigned short* __restrict__ Ag, const unsigned short* __restrict__ Bw,
    const float* __restrict__ bias, const int* __restrict__ off,
    const int* __restrict__ slot_token, unsigned short* __restrict__ Out)
{
    constexpr int NT = KD / 32;
    __shared__ __align__(16) unsigned short As[2][128 * 32];
    __shared__ __align__(16) unsigned short Bs[2][128 * 32];

    int s0 = blockIdx.x * 128;
    if (s0 >= off[E_EXP]) return;
    int e = 0;
    while (s0 >= off[e + 1]) e++;
    int n0 = blockIdx.y * 128;

    int tid = threadIdx.x;
    int wave = tid >> 6, lane = tid & 63;
    int lrow = lane & 15, quad = lane >> 4;
    int srow = lane >> 2;                       // 0..15: row within 16-row chunk
    int scol = ((lane & 3) ^ ((srow >> 1) & 3)) * 8;   // swizzled source chunk

    int r0 = 16 * wave + srow, r1 = r0 + 64;
    const unsigned short* a0;
    const unsigned short* a1;
    if constexpr (GATHER) {
        int t0 = slot_token[s0 + r0]; if (t0 < 0) t0 = 0;
        int t1 = slot_token[s0 + r1]; if (t1 < 0) t1 = 0;
        a0 = Ag + (size_t)t0 * KD + scol;
        a1 = Ag + (size_t)t1 * KD + scol;
    } else {
        a0 = Ag + (size_t)(s0 + r0) * KD + scol;
        a1 = Ag + (size_t)(s0 + r1) * KD + scol;
    }
    const unsigned short* wb = Bw + (size_t)e * ND * KD;
    const unsigned short* bp0 = wb + (size_t)(n0 + r0) * KD + scol;
    const unsigned short* bp1 = wb + (size_t)(n0 + r1) * KD + scol;

    int stA0 = (16 * wave) * 32;        // wave-uniform LDS staging offsets (shorts)
    int stA1 = (64 + 16 * wave) * 32;

    f32x4 acc[4][4];
    #pragma unroll
    for (int mi = 0; mi < 4; mi++)
        #pragma unroll
        for (int ni = 0; ni < 4; ni++) acc[mi][ni] = (f32x4){0.f, 0.f, 0.f, 0.f};

    int wr = (wave >> 1) * 64, wc = (wave & 1) * 64;
    int g = (quad ^ ((lrow >> 1) & 3)) * 8;     // unswizzled fragment chunk

    auto STAGE = [&](int b, int k) {
        GLD_LDS16(a0 + k,  &As[b][stA0]);
        GLD_LDS16(a1 + k,  &As[b][stA1]);
        GLD_LDS16(bp0 + k, &Bs[b][stA0]);
        GLD_LDS16(bp1 + k, &Bs[b][stA1]);
    };
    auto COMPUTE = [&](int b) {
        bf16x8 af[4], bfr[4];
        #pragma unroll
        for (int i = 0; i < 4; i++) {
            af[i]  = *(const bf16x8*)&As[b][(wr + i * 16 + lrow) * 32 + g];
            bfr[i] = *(const bf16x8*)&Bs[b][(wc + i * 16 + lrow) * 32 + g];
        }
        __builtin_amdgcn_s_setprio(1);
        #pragma unroll
        for (int mi = 0; mi < 4; mi++)
            #pragma unroll
            for (int ni = 0; ni < 4; ni++)
                acc[mi][ni] = __builtin_amdgcn_mfma_f32_16x16x32_bf16(
                    af[mi], bfr[ni], acc[mi][ni], 0, 0, 0);
        __builtin_amdgcn_s_setprio(0);
    };

    // prologue: steps 0 and 1 in flight (8 loads outstanding)
    STAGE(0, 0);
    STAGE(1, 32);
    for (int t = 0; t < NT - 1; ++t) {
        asm volatile("s_waitcnt vmcnt(4)" ::: "memory");   // step t landed
        asm volatile("s_barrier" ::: "memory");
        COMPUTE(t & 1);
        asm volatile("s_barrier" ::: "memory");            // all reads of buf done
        if (t + 2 < NT) STAGE(t & 1, (t + 2) * 32);
    }
    asm volatile("s_waitcnt vmcnt(0)" ::: "memory");       // final step landed
    asm volatile("s_barrier" ::: "memory");
    COMPUTE((NT - 1) & 1);
    asm volatile("s_barrier" ::: "memory");                // before scratch reuse

    // epilogue: bias(+relu) -> bf16, per-wave LDS repack -> coalesced 16B stores
    float bv[4];
    #pragma unroll
    for (int ni = 0; ni < 4; ni++)
        bv[ni] = bias[(size_t)e * ND + n0 + wc + ni * 16 + lrow];
    unsigned short* w = &As[0][0] + wave * 1024;   // 16 rows x 64 cols per wave
    #pragma unroll
    for (int mi = 0; mi < 4; mi++) {
        #pragma unroll
        for (int ni = 0; ni < 4; ni++)
            #pragma unroll
            for (int rr = 0; rr < 4; rr++) {
                float v = acc[mi][ni][rr] + bv[ni];
                if constexpr (RELU) v = fmaxf(v, 0.0f);
                w[(quad * 4 + rr) * 64 + ni * 16 + lrow] = f2bf(v);
            }
        // intra-wave LDS dependency only: no barrier needed
        int rd = lane >> 3, cc = (lane & 7) * 8;
        bf16x8 v0 = *(const bf16x8*)&w[rd * 64 + cc];
        bf16x8 v1 = *(const bf16x8*)&w[(8 + rd) * 64 + cc];
        size_t rowg = (size_t)(s0 + wr + mi * 16 + rd) * ND + n0 + wc + cc;
        *(bf16x8*)&Out[rowg] = v0;
        *(bf16x8*)&Out[rowg + 8 * (size_t)ND] = v1;
    }
}

// ---------------- combine: out[t] = g0*Y[slot0] + g1*Y[slot1] ----------------
__global__ __launch_bounds__(256) void combine_kernel(
    const unsigned short* __restrict__ Yb, const int* __restrict__ slot_of,
    const float* __restrict__ tk_g, float* __restrict__ out)
{
    int t = blockIdx.x * 2 + (threadIdx.x >> 7);
    int j = threadIdx.x & 127;                 // 8 elements per thread
    int sA = slot_of[t * 2], sB = slot_of[t * 2 + 1];
    float gA = tk_g[t * 2], gB = tk_g[t * 2 + 1];
    uint4 va = *(const uint4*)(Yb + (size_t)sA * D_DIM + j * 8);
    uint4 vb = *(const uint4*)(Yb + (size_t)sB * D_DIM + j * 8);
    const unsigned int* pa = (const unsigned int*)&va;
    const unsigned int* pb = (const unsigned int*)&vb;
    float o[8];
    #pragma unroll
    for (int i = 0; i < 4; i++) {
        float a_lo = __uint_as_float(pa[i] << 16);
        float a_hi = __uint_as_float(pa[i] & 0xffff0000u);
        float b_lo = __uint_as_float(pb[i] << 16);
        float b_hi = __uint_as_float(pb[i] & 0xffff0000u);
        o[i * 2 + 0] = gA * a_lo + gB * b_lo;
        o[i * 2 + 1] = gA * a_hi + gB * b_hi;
    }
    float* op = out + (size_t)t * D_DIM + j * 8;
    ((float4*)op)[0] = make_float4(o[0], o[1], o[2], o[3]);
    ((float4*)op)[1] = make_float4(o[4], o[5], o[6], o[7]);
}

extern "C" void kernel_launch(void* const* d_in, const int* in_sizes, int n_in,
                              void* d_out, int out_size, void* d_ws, size_t ws_size,
                              hipStream_t stream)
{
    const float* xf = (const float*)d_in[0];
    const float* wg = (const float*)d_in[1];
    const float* bg = (const float*)d_in[2];
    const float* w1 = (const float*)d_in[3];
    const float* b1 = (const float*)d_in[4];
    const float* w2 = (const float*)d_in[5];
    const float* b2 = (const float*)d_in[6];
    float* out = (float*)d_out;

    char* p = (char*)d_ws;
    int* off    = (int*)p;                              // 16 (9 used)
    int* tk_e   = off + 16;                             // 8192
    float* tk_g = (float*)(tk_e + T_TOK * 2);           // 8192
    int* slot_token = (int*)(tk_g + T_TOK * 2);         // 9216
    float* slot_gate = (float*)(slot_token + CAP);      // 9216
    int* slot_of = (int*)(slot_gate + CAP);             // 8192
    float* ent_part = (float*)(slot_of + T_TOK * 2);    // 1024
    size_t ofs = ((size_t)((char*)(ent_part + T_TOK / 4) - p) + 255) & ~(size_t)255;
    unsigned short* xb  = (unsigned short*)(p + ofs); ofs += (size_t)T_TOK * D_DIM * 2;
    unsigned short* w1t = (unsigned short*)(p + ofs); ofs += (size_t)E_EXP * D_DIM * H_DIM * 2;
    unsigned short* w2t = (unsigned short*)(p + ofs); ofs += (size_t)E_EXP * H_DIM * D_DIM * 2;
    unsigned short* Hb  = (unsigned short*)(p + ofs); ofs += (size_t)CAP * H_DIM * 2;
    unsigned short* Yb  = w1t;   // alias: w1t is dead after gemm1

    gating_kernel<<<T_TOK / 4, 256, 0, stream>>>(xf, wg, bg, xb, tk_e, tk_g, ent_part);
    route_kernel<<<1, 1024, 0, stream>>>(tk_e, tk_g, off, slot_token, slot_gate, slot_of,
                                         ent_part, out + (size_t)T_TOK * D_DIM);
    // w1 (E, D, H) -> w1t (E, H, D)
    tcvt_kernel<<<dim3(H_DIM / 64, D_DIM / 64, E_EXP), 256, 0, stream>>>(w1, w1t, D_DIM, H_DIM);
    // w2 (E, H, D) -> w2t (E, D, H)
    tcvt_kernel<<<dim3(D_DIM / 64, H_DIM / 64, E_EXP), 256, 0, stream>>>(w2, w2t, H_DIM, D_DIM);
    // GEMM1: Hb = relu(gather(xb) @ w1t[e]^T + b1[e])
    gemm_kernel<D_DIM, H_DIM, true, true>
        <<<dim3(TILES_M, H_DIM / 128), 256, 0, stream>>>(xb, w1t, b1, off, slot_token, Hb);
    // GEMM2: Yb = Hb @ w2t[e]^T + b2[e]
    gemm_kernel<H_DIM, D_DIM, false, false>
        <<<dim3(TILES_M, D_DIM / 128), 256, 0, stream>>>(Hb, w2t, b2, off, slot_token, Yb);
    combine_kernel<<<T_TOK / 2, 256, 0, stream>>>(Yb, slot_of, tk_g, out);
}